// Round 4
// baseline (101.132 us; speedup 1.0000x reference)
//
#include <hip/hip_runtime.h>
#include <hip/hip_bf16.h>
#include <math.h>

typedef __bf16 bf16;
typedef __attribute__((ext_vector_type(8))) __bf16 bf16x8;
typedef __attribute__((ext_vector_type(4))) __bf16 bf16x4;
typedef __attribute__((ext_vector_type(4))) float f32x4;

#define B_  2
#define T_  2048
#define C_  1024
#define H_  16
#define HD_ 64
#define WIN_ 256

// async global->LDS, 16B per lane, dest = wave-uniform base + lane*16
#define GLOAD16(g, l)                                                        \
  __builtin_amdgcn_global_load_lds(                                          \
      (const __attribute__((address_space(1))) void*)(g),                    \
      (__attribute__((address_space(3))) void*)(l), 16, 0, 0)

// ---------------- conversions ----------------

__global__ __launch_bounds__(256) void cvt_f32_bf16_k(const float* __restrict__ in,
                                                      bf16* __restrict__ out) {
  int idx = blockIdx.x * 256 + threadIdx.x;           // 4 elems per thread
  const float4 v = ((const float4*)in)[idx];
  bf16x4 o;
  o[0] = (bf16)v.x; o[1] = (bf16)v.y; o[2] = (bf16)v.z; o[3] = (bf16)v.w;
  ((bf16x4*)out)[idx] = o;
}

// W [K][N] f32  ->  WT [N][K] bf16
__global__ __launch_bounds__(256) void transpose_cvt_k(const float* __restrict__ W,
                                                       bf16* __restrict__ WT,
                                                       int K, int N) {
  __shared__ float t[32][33];
  int n0 = blockIdx.x * 32, k0 = blockIdx.y * 32;
  int tx = threadIdx.x, ty = threadIdx.y;
  #pragma unroll
  for (int i = 0; i < 32; i += 8)
    t[ty + i][tx] = W[(size_t)(k0 + ty + i) * N + (n0 + tx)];
  __syncthreads();
  #pragma unroll
  for (int i = 0; i < 32; i += 8)
    WT[(size_t)(n0 + ty + i) * K + (k0 + tx)] = (bf16)t[tx][ty + i];
}

// ---------------- 256x256 deep-pipelined MFMA GEMM (T2+T3+T4+T5) ----------------
// C[M][N] = A[M][K] * Bt[N][K]^T + bias[N]; 512 thr = 8 waves (2Mx4N),
// BK=64, LDS double-buffered 128 KiB, counted vmcnt(8), XOR-swizzled LDS.
// MODE 0: f32 out stride N.
// MODE 2: qkv split: cols [0,2C) -> bf16 out0 stride 2C;
//                    cols [2C,3C) -> V^T layout out1[((b*H+h)*64+d)*T+tok].

template <int MODE>
__global__ __launch_bounds__(512, 2) void gemm256_k(const bf16* __restrict__ A,
                                                    const bf16* __restrict__ Bt,
                                                    const float* __restrict__ bias,
                                                    void* __restrict__ out0,
                                                    void* __restrict__ out1,
                                                    int M, int N, int K) {
  const int bm = blockIdx.x * 256;
  const int bn = blockIdx.y * 256;
  const int tid  = threadIdx.x;
  const int wid  = tid >> 6;
  const int lane = tid & 63;
  const int wr = wid >> 2;           // 0..1 : M-half
  const int wc = wid & 3;            // 0..3 : N-quarter
  const int lr = lane & 15;
  const int g  = lane >> 4;

  __shared__ bf16 As[2][256][64];    // 64 KiB
  __shared__ bf16 Bs[2][256][64];    // 64 KiB

  f32x4 acc[8][4] = {};

  // ---- staging (inverse-swizzled source, linear LDS dest) ----
  // chunk j = wid*4+i covers rows j*8..j*8+7; lane l -> row +(l>>3), 16B piece
  // (l&7)^(l>>3) of that row (so LDS[r][c] holds global [r][c ^ ((r&7)<<4B)]).
  const int rloc = lane >> 3;                 // 0..7
  const int scol = ((lane & 7) ^ rloc) << 3;  // bf16 col of this lane's 16B
  const bf16* A0 = A  + (size_t)(bm + wid * 32 + rloc) * K + scol;
  const bf16* B0 = Bt + (size_t)(bn + wid * 32 + rloc) * K + scol;
  bf16* Al[2] = { &As[0][wid * 32][0], &As[1][wid * 32][0] };
  bf16* Bl[2] = { &Bs[0][wid * 32][0], &Bs[1][wid * 32][0] };

  #define STAGE(buf, kt)                                                     \
    do {                                                                     \
      _Pragma("unroll")                                                      \
      for (int i = 0; i < 4; ++i) {                                          \
        GLOAD16(A0 + (size_t)(i * 8) * K + ((kt) << 6), Al[buf] + i * 512);  \
        GLOAD16(B0 + (size_t)(i * 8) * K + ((kt) << 6), Bl[buf] + i * 512);  \
      }                                                                      \
    } while (0)

  const int NT = K >> 6;
  const int arow = wr * 128 + lr;    // A fragment row base
  const int brow = wc * 64 + lr;     // B fragment row base
  const int sw   = lr & 7;           // read-side swizzle

  STAGE(0, 0);

  for (int kt = 0; kt < NT; ++kt) {
    if (kt + 1 < NT) {
      STAGE((kt + 1) & 1, kt + 1);
      asm volatile("s_waitcnt vmcnt(8)" ::: "memory");  // prev tile landed
    } else {
      asm volatile("s_waitcnt vmcnt(0)" ::: "memory");
    }
    __builtin_amdgcn_s_barrier();

    const bf16 (*Ab)[64] = As[kt & 1];
    const bf16 (*Bb)[64] = Bs[kt & 1];
    #pragma unroll
    for (int s = 0; s < 2; ++s) {
      bf16x8 af[8], bfv[4];
      #pragma unroll
      for (int m = 0; m < 8; ++m)
        af[m] = *(const bf16x8*)&Ab[arow + m * 16][(((s << 2) + g) ^ sw) << 3];
      #pragma unroll
      for (int n = 0; n < 4; ++n)
        bfv[n] = *(const bf16x8*)&Bb[brow + n * 16][(((s << 2) + g) ^ sw) << 3];
      __builtin_amdgcn_s_setprio(1);
      #pragma unroll
      for (int m = 0; m < 8; ++m)
        #pragma unroll
        for (int n = 0; n < 4; ++n)
          acc[m][n] = __builtin_amdgcn_mfma_f32_16x16x32_bf16(af[m], bfv[n], acc[m][n], 0, 0, 0);
      __builtin_amdgcn_s_setprio(0);
    }
    asm volatile("" ::: "memory");
    __builtin_amdgcn_s_barrier();    // reads done before next STAGE overwrites
  }
  #undef STAGE

  // ---- epilogue: D elem (reg r, lane l) -> row=(l>>4)*4+r, col=l&15 ----
  const int orow = g * 4;
  #pragma unroll
  for (int n = 0; n < 4; ++n) {
    const int gn = bn + wc * 64 + n * 16 + lr;
    const float bv = bias[gn];
    #pragma unroll
    for (int m = 0; m < 8; ++m) {
      const int gm0 = bm + wr * 128 + m * 16 + orow;
      if (MODE == 0) {
        #pragma unroll
        for (int r = 0; r < 4; ++r)
          ((float*)out0)[(size_t)(gm0 + r) * N + gn] = acc[m][n][r] + bv;
      } else { // MODE 2
        if (bn + wc * 64 + n * 16 < 2 * C_) {
          #pragma unroll
          for (int r = 0; r < 4; ++r)
            ((bf16*)out0)[(size_t)(gm0 + r) * (2 * C_) + gn] = (bf16)(acc[m][n][r] + bv);
        } else {
          const int vcol = gn - 2 * C_;
          const int h = vcol >> 6, d = vcol & 63;
          const int b = gm0 >> 11, tok = gm0 & (T_ - 1);   // gm0 % 4 == 0
          bf16x4 o;
          #pragma unroll
          for (int r = 0; r < 4; ++r) o[r] = (bf16)(acc[m][n][r] + bv);
          *(bf16x4*)&((bf16*)out1)[(((size_t)b * H_ + h) * HD_ + d) * T_ + tok] = o;
        }
      }
    }
  }
}

// ---------------- m97-style GEMM (kept for proj) ----------------

template <int BM, int MODE>
__global__ __launch_bounds__(256) void gemm_lds_k(const bf16* __restrict__ A,
                                                  const bf16* __restrict__ Bt,
                                                  const float* __restrict__ bias,
                                                  void* __restrict__ out0,
                                                  void* __restrict__ out1,
                                                  int M, int N, int K) {
  constexpr int FM = BM / 32;
  const int bm = blockIdx.x * BM;
  const int bn = blockIdx.y * 128;
  const int tid  = threadIdx.x;
  const int wid  = tid >> 6;
  const int lane = tid & 63;
  const int wm = (wid >> 1) * (BM / 2);
  const int wn = (wid & 1) * 64;
  const int lr = lane & 15;
  const int g  = lane >> 4;

  __shared__ bf16 As[BM][32];
  __shared__ bf16 Bs[128][32];

  f32x4 acc[FM][4] = {};

  const int srow = lane >> 2;
  const int scol = (lane & 3) * 8;
  const bf16* Abase = A  + (size_t)bm * K;
  const bf16* Bbase = Bt + (size_t)bn * K;

  for (int k0 = 0; k0 < K; k0 += 32) {
    #pragma unroll
    for (int i = 0; i < BM / 64; ++i) {
      const int c = wid * (BM / 64) + i;
      GLOAD16(Abase + (size_t)(c * 16 + srow) * K + k0 + scol, &As[c * 16][0]);
    }
    #pragma unroll
    for (int i = 0; i < 2; ++i) {
      const int c = wid * 2 + i;
      GLOAD16(Bbase + (size_t)(c * 16 + srow) * K + k0 + scol, &Bs[c * 16][0]);
    }
    __syncthreads();

    bf16x8 af[FM], bfr[4];
    #pragma unroll
    for (int m = 0; m < FM; ++m) af[m]  = *(const bf16x8*)&As[wm + m * 16 + lr][g * 8];
    #pragma unroll
    for (int n = 0; n < 4; ++n)  bfr[n] = *(const bf16x8*)&Bs[wn + n * 16 + lr][g * 8];

    #pragma unroll
    for (int m = 0; m < FM; ++m)
      #pragma unroll
      for (int n = 0; n < 4; ++n)
        acc[m][n] = __builtin_amdgcn_mfma_f32_16x16x32_bf16(af[m], bfr[n], acc[m][n], 0, 0, 0);
    __syncthreads();
  }

  const int orow = g * 4;
  const int ocol = lr;
  #pragma unroll
  for (int m = 0; m < FM; ++m)
    #pragma unroll
    for (int n = 0; n < 4; ++n) {
      const int gn  = bn + wn + n * 16 + ocol;
      const int gm0 = bm + wm + m * 16 + orow;
      const float bv = bias[gn];
      if (MODE == 0) {
        #pragma unroll
        for (int r = 0; r < 4; ++r)
          ((float*)out0)[(size_t)(gm0 + r) * N + gn] = acc[m][n][r] + bv;
      }
    }
}

// ---------------- windowed flash attention (MFMA) ----------------

__global__ __launch_bounds__(256) void attn_mfma_k(const bf16* __restrict__ qk,
                                                   const bf16* __restrict__ vt,
                                                   bf16* __restrict__ y) {
  const int q0 = blockIdx.x * 64;
  const int h  = blockIdx.y;
  const int b  = blockIdx.z;
  const int tid  = threadIdx.x;
  const int wid  = tid >> 6;
  const int lane = tid & 63;
  const int lr = lane & 15;
  const int g  = lane >> 4;

  __shared__ bf16 Ks[64][72];          // [key][d]
  __shared__ bf16 Vs[64][72];          // [d][key]  (V^T)
  __shared__ bf16 Ps[4][16][72];       // per-wave: [q][key]

  const int qrow = q0 + wid * 16 + lr;
  const bf16* qptr = qk + ((size_t)(b * T_ + qrow)) * (2 * C_) + h * HD_;
  bf16x8 qf[2];
  qf[0] = *(const bf16x8*)(qptr + g * 8);
  qf[1] = *(const bf16x8*)(qptr + 32 + g * 8);

  float m = -1e30f, l = 0.f;
  f32x4 yacc[4] = {};

  const int kt_lo = (blockIdx.x >= 4) ? (int)blockIdx.x - 4 : 0;
  for (int kt = kt_lo; kt <= (int)blockIdx.x; ++kt) {
    __syncthreads();
    #pragma unroll
    for (int i = 0; i < 2; ++i) {
      int cc = tid + i * 256;
      int rr = cc >> 3;
      int c0 = (cc & 7) * 8;
      *(bf16x8*)&Ks[rr][c0] = *(const bf16x8*)&qk[((size_t)(b * T_) + kt * 64 + rr) * (2 * C_) + C_ + h * HD_ + c0];
      *(bf16x8*)&Vs[rr][c0] = *(const bf16x8*)&vt[(((size_t)b * H_ + h) * HD_ + rr) * T_ + kt * 64 + c0];
    }
    __syncthreads();

    f32x4 sacc[4] = {};
    #pragma unroll
    for (int t = 0; t < 4; ++t)
      #pragma unroll
      for (int s = 0; s < 2; ++s)
        sacc[t] = __builtin_amdgcn_mfma_f32_16x16x32_bf16(
            *(const bf16x8*)&Ks[t * 16 + lr][s * 32 + g * 8], qf[s], sacc[t], 0, 0, 0);

    float pv[4][4];
    float rmax = -1e30f;
    #pragma unroll
    for (int t = 0; t < 4; ++t)
      #pragma unroll
      for (int r = 0; r < 4; ++r) {
        const int key = kt * 64 + t * 16 + g * 4 + r;
        const bool valid = (key <= qrow) && (qrow - key <= WIN_);
        const float sv = valid ? sacc[t][r] * 0.125f : -__builtin_inff();
        pv[t][r] = sv;
        rmax = fmaxf(rmax, sv);
      }
    rmax = fmaxf(rmax, __shfl_xor(rmax, 16));
    rmax = fmaxf(rmax, __shfl_xor(rmax, 32));

    const float mnew = fmaxf(m, rmax);
    const float alpha = __expf(m - mnew);
    m = mnew;
    float lsum = 0.f;
    #pragma unroll
    for (int t = 0; t < 4; ++t)
      #pragma unroll
      for (int r = 0; r < 4; ++r) {
        const float e = __expf(pv[t][r] - mnew);
        pv[t][r] = e;
        lsum += e;
      }
    lsum += __shfl_xor(lsum, 16);
    lsum += __shfl_xor(lsum, 32);
    l = l * alpha + lsum;

    #pragma unroll
    for (int t = 0; t < 4; ++t) {
      bf16x4 pk;
      #pragma unroll
      for (int r = 0; r < 4; ++r) pk[r] = (bf16)pv[t][r];
      *(bf16x4*)&Ps[wid][lr][t * 16 + g * 4] = pk;
    }

    float al[4];
    #pragma unroll
    for (int r = 0; r < 4; ++r) al[r] = __shfl(alpha, g * 4 + r);
    #pragma unroll
    for (int t = 0; t < 4; ++t)
      #pragma unroll
      for (int r = 0; r < 4; ++r) yacc[t][r] *= al[r];

    bf16x8 pf[2];
    pf[0] = *(const bf16x8*)&Ps[wid][lr][g * 8];
    pf[1] = *(const bf16x8*)&Ps[wid][lr][32 + g * 8];
    #pragma unroll
    for (int t = 0; t < 4; ++t)
      #pragma unroll
      for (int s = 0; s < 2; ++s)
        yacc[t] = __builtin_amdgcn_mfma_f32_16x16x32_bf16(
            pf[s], *(const bf16x8*)&Vs[t * 16 + lr][s * 32 + g * 8], yacc[t], 0, 0, 0);
  }

  float li[4];
  #pragma unroll
  for (int r = 0; r < 4; ++r) li[r] = 1.f / __shfl(l, g * 4 + r);
  #pragma unroll
  for (int t = 0; t < 4; ++t)
    #pragma unroll
    for (int r = 0; r < 4; ++r) {
      const int tok = q0 + wid * 16 + g * 4 + r;
      y[((size_t)(b * T_ + tok)) * C_ + h * HD_ + t * 16 + lr] = (bf16)(yacc[t][r] * li[r]);
    }
}

// ---------------- launch ----------------

extern "C" void kernel_launch(void* const* d_in, const int* in_sizes, int n_in,
                              void* d_out, int out_size, void* d_ws, size_t ws_size,
                              hipStream_t stream) {
  const float* x     = (const float*)d_in[0];
  const float* Wqkv  = (const float*)d_in[1];
  const float* bqkv  = (const float*)d_in[2];
  const float* Wproj = (const float*)d_in[3];
  const float* bproj = (const float*)d_in[4];
  float* out = (float*)d_out;

  const size_t SZ_QK  = (size_t)B_ * T_ * 2 * C_ * sizeof(bf16);   // 16 MB
  const size_t SZ_VT  = (size_t)B_ * H_ * HD_ * T_ * sizeof(bf16); //  8 MB
  const size_t SZ_XB  = (size_t)B_ * T_ * C_ * sizeof(bf16);       //  8 MB
  const size_t SZ_WQT = (size_t)3 * C_ * C_ * sizeof(bf16);        //  6 MB
  const size_t SZ_WPT = (size_t)C_ * C_ * sizeof(bf16);            //  2 MB
  const size_t NEED   = SZ_QK + SZ_VT + SZ_XB + SZ_WQT + SZ_WPT + SZ_XB;
  if (ws_size < NEED) return;

  char* ws = (char*)d_ws;
  bf16* qkb    = (bf16*)(ws);
  bf16* vtb    = (bf16*)(ws + SZ_QK);
  bf16* xb     = (bf16*)(ws + SZ_QK + SZ_VT);
  bf16* wqkvT  = (bf16*)(ws + SZ_QK + SZ_VT + SZ_XB);
  bf16* wprojT = (bf16*)(ws + SZ_QK + SZ_VT + SZ_XB + SZ_WQT);
  bf16* yb     = (bf16*)(ws + SZ_QK + SZ_VT + SZ_XB + SZ_WQT + SZ_WPT);

  cvt_f32_bf16_k<<<4096, 256, 0, stream>>>(x, xb);
  transpose_cvt_k<<<dim3(3 * C_ / 32, C_ / 32), dim3(32, 8), 0, stream>>>(Wqkv, wqkvT, C_, 3 * C_);
  transpose_cvt_k<<<dim3(C_ / 32, C_ / 32), dim3(32, 8), 0, stream>>>(Wproj, wprojT, C_, C_);

  // qkv = x @ Wqkv + bqkv  (Q,K -> qkb [B,T,2C]; V -> vtb [B,H,64,T])
  gemm256_k<2><<<dim3((B_ * T_) / 256, (3 * C_) / 256), 512, 0, stream>>>(
      xb, wqkvT, bqkv, qkb, vtb, B_ * T_, 3 * C_, C_);

  attn_mfma_k<<<dim3(T_ / 64, H_, B_), 256, 0, stream>>>(qkb, vtb, yb);

  // out = y @ Wproj + bproj (f32)
  gemm_lds_k<64, 0><<<dim3((B_ * T_) / 64, C_ / 128), 256, 0, stream>>>(
      yb, wprojT, bproj, out, nullptr, B_ * T_, C_, C_);
}

// Round 5
// 96.773 us; speedup vs baseline: 1.0450x; 1.0450x over previous
//
#include <hip/hip_runtime.h>
#include <hip/hip_bf16.h>
#include <math.h>

typedef __bf16 bf16;
typedef __attribute__((ext_vector_type(8))) __bf16 bf16x8;
typedef __attribute__((ext_vector_type(4))) __bf16 bf16x4;
typedef __attribute__((ext_vector_type(4))) float f32x4;

#define B_  2
#define T_  2048
#define C_  1024
#define H_  16
#define HD_ 64
#define WIN_ 256

// async global->LDS, 16B per lane, dest = wave-uniform base + lane*16
#define GLOAD16(g, l)                                                        \
  __builtin_amdgcn_global_load_lds(                                          \
      (const __attribute__((address_space(1))) void*)(g),                    \
      (__attribute__((address_space(3))) void*)(l), 16, 0, 0)

// ---------------- conversions ----------------

__global__ __launch_bounds__(256) void cvt_f32_bf16_k(const float* __restrict__ in,
                                                      bf16* __restrict__ out) {
  int idx = blockIdx.x * 256 + threadIdx.x;           // 4 elems per thread
  const float4 v = ((const float4*)in)[idx];
  bf16x4 o;
  o[0] = (bf16)v.x; o[1] = (bf16)v.y; o[2] = (bf16)v.z; o[3] = (bf16)v.w;
  ((bf16x4*)out)[idx] = o;
}

// W [K][N] f32  ->  WT [N][K] bf16
__global__ __launch_bounds__(256) void transpose_cvt_k(const float* __restrict__ W,
                                                       bf16* __restrict__ WT,
                                                       int K, int N) {
  __shared__ float t[32][33];
  int n0 = blockIdx.x * 32, k0 = blockIdx.y * 32;
  int tx = threadIdx.x, ty = threadIdx.y;
  #pragma unroll
  for (int i = 0; i < 32; i += 8)
    t[ty + i][tx] = W[(size_t)(k0 + ty + i) * N + (n0 + tx)];
  __syncthreads();
  #pragma unroll
  for (int i = 0; i < 32; i += 8)
    WT[(size_t)(n0 + ty + i) * K + (k0 + tx)] = (bf16)t[tx][ty + i];
}

// ---------------- deep-pipelined MFMA GEMM ----------------
// C[M][N] = A[M][K] * Bt[N][K]^T + bias[N].
// TMxTN tile, BK=32, WM*WN waves; 4 LDS buffers, stage 2 K-tiles ahead,
// counted vmcnt(8) (= 4 loads/tile x 2 tiles in flight), ONE s_barrier/tile,
// XOR-swizzled LDS (inverse on global src, forward on ds_read col).
// MODE 0: f32 out stride N.
// MODE 2: qkv split: cols [0,2C) -> bf16 out0 stride 2C;
//                    cols [2C,3C) -> V^T layout out1[((b*H+h)*64+d)*T+tok].

template <int TM, int TN, int WM, int WN, int MODE>
__global__ __launch_bounds__(WM * WN * 64, 2)
void gemm_dp_k(const bf16* __restrict__ A, const bf16* __restrict__ Bt,
               const float* __restrict__ bias,
               void* __restrict__ out0, void* __restrict__ out1,
               int M, int N, int K) {
  constexpr int NW    = WM * WN;
  constexpr int WROWS = TM / WM;
  constexpr int WCOLS = TN / WN;
  constexpr int FM    = WROWS / 16;
  constexpr int FN    = WCOLS / 16;
  constexpr int CA    = TM / 16 / NW;   // A 1KB-chunks per wave per tile
  constexpr int CB    = TN / 16 / NW;

  const int bm = blockIdx.x * TM;
  const int bn = blockIdx.y * TN;
  const int tid  = threadIdx.x;
  const int wid  = tid >> 6;
  const int lane = tid & 63;
  const int wr = wid / WN;
  const int wc = wid % WN;
  const int lr = lane & 15;
  const int g  = lane >> 4;

  __shared__ bf16 As[4][TM][32];
  __shared__ bf16 Bs[4][TN][32];

  f32x4 acc[FM][FN] = {};

  // staging: chunk = 16 rows x 64B; lane -> row (lane>>2), 16B piece (lane&3),
  // piece XOR (row&3) on the GLOBAL side (LDS dest stays linear).
  const int rloc = lane >> 2;                       // 0..15
  const int scol = (((lane & 3) ^ (rloc & 3))) * 8; // bf16 col of this lane's 16B
  const bf16* aSrc = A  + (size_t)(bm + wid * CA * 16 + rloc) * K + scol;
  const bf16* bSrc = Bt + (size_t)(bn + wid * CB * 16 + rloc) * K + scol;

  #define STAGE_DP(buf, kt)                                                   \
    do {                                                                      \
      _Pragma("unroll")                                                       \
      for (int i = 0; i < CA; ++i)                                            \
        GLOAD16(aSrc + (size_t)(i * 16) * K + (kt) * 32,                      \
                &As[buf][(wid * CA + i) * 16][0]);                            \
      _Pragma("unroll")                                                       \
      for (int i = 0; i < CB; ++i)                                            \
        GLOAD16(bSrc + (size_t)(i * 16) * K + (kt) * 32,                      \
                &Bs[buf][(wid * CB + i) * 16][0]);                            \
    } while (0)

  const int NT = K >> 5;
  const int kc = (g ^ (lr & 3)) * 8;   // swizzled read col (bf16 idx)

  STAGE_DP(0, 0);
  STAGE_DP(1, 1);

  for (int t = 0; t < NT; ++t) {
    const int buf = t & 3;
    if (t + 2 < NT) {
      STAGE_DP((t + 2) & 3, t + 2);
      asm volatile("s_waitcnt vmcnt(8)" ::: "memory");   // tile t landed
    } else if (t + 1 < NT) {
      asm volatile("s_waitcnt vmcnt(4)" ::: "memory");
    } else {
      asm volatile("s_waitcnt vmcnt(0)" ::: "memory");
    }
    __builtin_amdgcn_s_barrier();
    asm volatile("" ::: "memory");

    bf16x8 af[FM], bfv[FN];
    #pragma unroll
    for (int m = 0; m < FM; ++m)
      af[m] = *(const bf16x8*)&As[buf][wr * WROWS + m * 16 + lr][kc];
    #pragma unroll
    for (int n = 0; n < FN; ++n)
      bfv[n] = *(const bf16x8*)&Bs[buf][wc * WCOLS + n * 16 + lr][kc];

    __builtin_amdgcn_s_setprio(1);
    #pragma unroll
    for (int m = 0; m < FM; ++m)
      #pragma unroll
      for (int n = 0; n < FN; ++n)
        acc[m][n] = __builtin_amdgcn_mfma_f32_16x16x32_bf16(af[m], bfv[n], acc[m][n], 0, 0, 0);
    __builtin_amdgcn_s_setprio(0);
  }
  #undef STAGE_DP

  // epilogue: D elem (reg r, lane l) -> row=(l>>4)*4+r, col=l&15
  const int orow = g * 4;
  #pragma unroll
  for (int n = 0; n < FN; ++n) {
    const int nbase = bn + wc * WCOLS + n * 16;
    const int gn = nbase + lr;
    const float bv = bias[gn];
    #pragma unroll
    for (int m = 0; m < FM; ++m) {
      const int gm0 = bm + wr * WROWS + m * 16 + orow;
      if (MODE == 0) {
        #pragma unroll
        for (int r = 0; r < 4; ++r)
          ((float*)out0)[(size_t)(gm0 + r) * N + gn] = acc[m][n][r] + bv;
      } else { // MODE 2
        if (nbase < 2 * C_) {
          #pragma unroll
          for (int r = 0; r < 4; ++r)
            ((bf16*)out0)[(size_t)(gm0 + r) * (2 * C_) + gn] = (bf16)(acc[m][n][r] + bv);
        } else {
          const int vcol = gn - 2 * C_;
          const int h = vcol >> 6, d = vcol & 63;
          const int b = gm0 >> 11, tok = gm0 & (T_ - 1);   // gm0 % 4 == 0
          bf16x4 o;
          #pragma unroll
          for (int r = 0; r < 4; ++r) o[r] = (bf16)(acc[m][n][r] + bv);
          *(bf16x4*)&((bf16*)out1)[(((size_t)b * H_ + h) * HD_ + d) * T_ + tok] = o;
        }
      }
    }
  }
}

// ---------------- windowed flash attention (MFMA) ----------------

__global__ __launch_bounds__(256) void attn_mfma_k(const bf16* __restrict__ qk,
                                                   const bf16* __restrict__ vt,
                                                   bf16* __restrict__ y) {
  const int q0 = blockIdx.x * 64;
  const int h  = blockIdx.y;
  const int b  = blockIdx.z;
  const int tid  = threadIdx.x;
  const int wid  = tid >> 6;
  const int lane = tid & 63;
  const int lr = lane & 15;
  const int g  = lane >> 4;

  __shared__ bf16 Ks[64][72];          // [key][d]
  __shared__ bf16 Vs[64][72];          // [d][key]  (V^T)
  __shared__ bf16 Ps[4][16][72];       // per-wave: [q][key]

  const int qrow = q0 + wid * 16 + lr;
  const bf16* qptr = qk + ((size_t)(b * T_ + qrow)) * (2 * C_) + h * HD_;
  bf16x8 qf[2];
  qf[0] = *(const bf16x8*)(qptr + g * 8);
  qf[1] = *(const bf16x8*)(qptr + 32 + g * 8);

  float m = -1e30f, l = 0.f;
  f32x4 yacc[4] = {};

  const int kt_lo = (blockIdx.x >= 4) ? (int)blockIdx.x - 4 : 0;
  for (int kt = kt_lo; kt <= (int)blockIdx.x; ++kt) {
    __syncthreads();
    #pragma unroll
    for (int i = 0; i < 2; ++i) {
      int cc = tid + i * 256;
      int rr = cc >> 3;
      int c0 = (cc & 7) * 8;
      *(bf16x8*)&Ks[rr][c0] = *(const bf16x8*)&qk[((size_t)(b * T_) + kt * 64 + rr) * (2 * C_) + C_ + h * HD_ + c0];
      *(bf16x8*)&Vs[rr][c0] = *(const bf16x8*)&vt[(((size_t)b * H_ + h) * HD_ + rr) * T_ + kt * 64 + c0];
    }
    __syncthreads();

    f32x4 sacc[4] = {};
    #pragma unroll
    for (int t = 0; t < 4; ++t)
      #pragma unroll
      for (int s = 0; s < 2; ++s)
        sacc[t] = __builtin_amdgcn_mfma_f32_16x16x32_bf16(
            *(const bf16x8*)&Ks[t * 16 + lr][s * 32 + g * 8], qf[s], sacc[t], 0, 0, 0);

    float pv[4][4];
    float rmax = -1e30f;
    #pragma unroll
    for (int t = 0; t < 4; ++t)
      #pragma unroll
      for (int r = 0; r < 4; ++r) {
        const int key = kt * 64 + t * 16 + g * 4 + r;
        const bool valid = (key <= qrow) && (qrow - key <= WIN_);
        const float sv = valid ? sacc[t][r] * 0.125f : -__builtin_inff();
        pv[t][r] = sv;
        rmax = fmaxf(rmax, sv);
      }
    rmax = fmaxf(rmax, __shfl_xor(rmax, 16));
    rmax = fmaxf(rmax, __shfl_xor(rmax, 32));

    const float mnew = fmaxf(m, rmax);
    const float alpha = __expf(m - mnew);
    m = mnew;
    float lsum = 0.f;
    #pragma unroll
    for (int t = 0; t < 4; ++t)
      #pragma unroll
      for (int r = 0; r < 4; ++r) {
        const float e = __expf(pv[t][r] - mnew);
        pv[t][r] = e;
        lsum += e;
      }
    lsum += __shfl_xor(lsum, 16);
    lsum += __shfl_xor(lsum, 32);
    l = l * alpha + lsum;

    #pragma unroll
    for (int t = 0; t < 4; ++t) {
      bf16x4 pk;
      #pragma unroll
      for (int r = 0; r < 4; ++r) pk[r] = (bf16)pv[t][r];
      *(bf16x4*)&Ps[wid][lr][t * 16 + g * 4] = pk;
    }

    float al[4];
    #pragma unroll
    for (int r = 0; r < 4; ++r) al[r] = __shfl(alpha, g * 4 + r);
    #pragma unroll
    for (int t = 0; t < 4; ++t)
      #pragma unroll
      for (int r = 0; r < 4; ++r) yacc[t][r] *= al[r];

    bf16x8 pf[2];
    pf[0] = *(const bf16x8*)&Ps[wid][lr][g * 8];
    pf[1] = *(const bf16x8*)&Ps[wid][lr][32 + g * 8];
    #pragma unroll
    for (int t = 0; t < 4; ++t)
      #pragma unroll
      for (int s = 0; s < 2; ++s)
        yacc[t] = __builtin_amdgcn_mfma_f32_16x16x32_bf16(
            pf[s], *(const bf16x8*)&Vs[t * 16 + lr][s * 32 + g * 8], yacc[t], 0, 0, 0);
  }

  float li[4];
  #pragma unroll
  for (int r = 0; r < 4; ++r) li[r] = 1.f / __shfl(l, g * 4 + r);
  #pragma unroll
  for (int t = 0; t < 4; ++t)
    #pragma unroll
    for (int r = 0; r < 4; ++r) {
      const int tok = q0 + wid * 16 + g * 4 + r;
      y[((size_t)(b * T_ + tok)) * C_ + h * HD_ + t * 16 + lr] = (bf16)(yacc[t][r] * li[r]);
    }
}

// ---------------- launch ----------------

extern "C" void kernel_launch(void* const* d_in, const int* in_sizes, int n_in,
                              void* d_out, int out_size, void* d_ws, size_t ws_size,
                              hipStream_t stream) {
  const float* x     = (const float*)d_in[0];
  const float* Wqkv  = (const float*)d_in[1];
  const float* bqkv  = (const float*)d_in[2];
  const float* Wproj = (const float*)d_in[3];
  const float* bproj = (const float*)d_in[4];
  float* out = (float*)d_out;

  const size_t SZ_QK  = (size_t)B_ * T_ * 2 * C_ * sizeof(bf16);   // 16 MB
  const size_t SZ_VT  = (size_t)B_ * H_ * HD_ * T_ * sizeof(bf16); //  8 MB
  const size_t SZ_XB  = (size_t)B_ * T_ * C_ * sizeof(bf16);       //  8 MB
  const size_t SZ_WQT = (size_t)3 * C_ * C_ * sizeof(bf16);        //  6 MB
  const size_t SZ_WPT = (size_t)C_ * C_ * sizeof(bf16);            //  2 MB
  const size_t NEED   = SZ_QK + SZ_VT + SZ_XB + SZ_WQT + SZ_WPT + SZ_XB;
  if (ws_size < NEED) return;

  char* ws = (char*)d_ws;
  bf16* qkb    = (bf16*)(ws);
  bf16* vtb    = (bf16*)(ws + SZ_QK);
  bf16* xb     = (bf16*)(ws + SZ_QK + SZ_VT);
  bf16* wqkvT  = (bf16*)(ws + SZ_QK + SZ_VT + SZ_XB);
  bf16* wprojT = (bf16*)(ws + SZ_QK + SZ_VT + SZ_XB + SZ_WQT);
  bf16* yb     = (bf16*)(ws + SZ_QK + SZ_VT + SZ_XB + SZ_WQT + SZ_WPT);

  cvt_f32_bf16_k<<<4096, 256, 0, stream>>>(x, xb);
  transpose_cvt_k<<<dim3(3 * C_ / 32, C_ / 32), dim3(32, 8), 0, stream>>>(Wqkv, wqkvT, C_, 3 * C_);
  transpose_cvt_k<<<dim3(C_ / 32, C_ / 32), dim3(32, 8), 0, stream>>>(Wproj, wprojT, C_, C_);

  // qkv = x @ Wqkv + bqkv  (Q,K -> qkb [B,T,2C]; V -> vtb [B,H,64,T])
  gemm_dp_k<256, 256, 2, 4, 2><<<dim3((B_ * T_) / 256, (3 * C_) / 256), 512, 0, stream>>>(
      xb, wqkvT, bqkv, qkb, vtb, B_ * T_, 3 * C_, C_);

  attn_mfma_k<<<dim3(T_ / 64, H_, B_), 256, 0, stream>>>(qkb, vtb, yb);

  // out = y @ Wproj + bproj (f32); 128x128 tiles -> 256 blocks = full CU fill
  gemm_dp_k<128, 128, 2, 2, 0><<<dim3((B_ * T_) / 128, C_ / 128), 256, 0, stream>>>(
      yb, wprojT, bproj, out, nullptr, B_ * T_, C_, C_);
}